// Round 5
// baseline (236.572 us; speedup 1.0000x reference)
//
#include <hip/hip_runtime.h>

// x: [8, 1, 160, 160, 160] fp32; log_sigma: [3] fp32; out: scalar fp32.
// loss = -(sum over 3816 (b,axis,pair) of exp(-sq/(2*sigma_axis^2))) / 3816.
//
// R5: STREAMING decomposition. R1-R4 (4 different structures) all ran 77-85us
// => the access SHAPE (100KB slice hops, 640B row fragments, wave straddling
// rows, contended atomic flush) was the wall, not scheduling. Now: block =
// (b, slice d); streams slice d and d+1 linearly (wave-contiguous 1KB lines,
// like the 6.8TB/s fill kernel). col = t%40 fixed -> aW[4] regs; row = t/40+8j
// -> aH[20] regs keyed by compile-time j; pair d owned entirely by the block
// -> aD scalar. Private per-block output slot; NO global atomics anywhere.

constexpr int Wd4 = 40;              // float4 per row
constexpr int SLICE4 = 6400;         // float4 per slice
constexpr long BSTR4 = 160L * 6400;  // float4 per batch
constexpr int NB = 8;
constexpr int ND = 160;
constexpr int NPAIR = 159;
constexpr int NKEY = 3 * NB * NPAIR;      // 3816
constexpr int BLK_STRIDE = 384;           // floats per private ws slot
constexpr int NBLK = NB * ND;             // 1280
constexpr int PART_OFF = NBLK * BLK_STRIDE;
constexpr int NFIN = 60;                  // reduce blocks

__device__ __forceinline__ float sq4(const float4& a, const float4& c) {
    float e0 = a.x - c.x, e1 = a.y - c.y, e2 = a.z - c.z, e3 = a.w - c.w;
    return e0 * e0 + e1 * e1 + e2 * e2 + e3 * e3;
}

// 1280 blocks x 320 threads. Block handles slice (b,d): w/h diffs of slice d,
// d-diff vs slice d+1 (if d<159). ws slot: [0]=aD, [1..160]=H[row], [161..320]=W[col].
__global__ __launch_bounds__(320) void diff3_kernel(const float* __restrict__ x,
                                                    float* __restrict__ ws) {
    __shared__ float ldsH[20][321];   // +1 pad: conflict-free transpose reads
    __shared__ float accW[160];
    __shared__ float accD;

    const int t = threadIdx.x;
    const int bid = blockIdx.x;
    // XCD swizzle: xcd = bid%8 gets contiguous d-range for L2 slice reuse
    const int xcd = bid & 7;
    const int idx = bid >> 3;        // 0..159
    const int b = idx / 20;
    const int d = xcd * 20 + idx % 20;
    const bool hasNext = (d < 159);

    const int c4 = t % 40;           // fixed float4-column
    const int r0 = t / 40;           // row base (row = r0 + 8j)
    const bool sOK = (c4 < 39);

    if (t < 160) accW[t] = 0.f;
    if (t == 0)  accD = 0.f;
    __syncthreads();

    const float4* curp = (const float4*)x + (size_t)b * BSTR4 + (size_t)d * SLICE4 + t;
    const float4* nxtp = curp + SLICE4;

    float aW0 = 0.f, aW1 = 0.f, aW2 = 0.f, aW3 = 0.f;
    float aD = 0.f;
    float aH[20];
#pragma unroll
    for (int j = 0; j < 20; ++j) aH[j] = 0.f;

#pragma unroll
    for (int j = 0; j < 20; ++j) {
        const float4 v = curp[320 * j];
        float4 nv;
        if (hasNext) nv = nxtp[320 * j];
        float4 hv;
        const bool hok = (j < 19) || (r0 < 7);   // row r0+8j <= 158
        if (hok) hv = curp[320 * j + Wd4];
        float sb = 0.f;
        if (sOK) sb = ((const float*)(curp + 320 * j))[4];

        float dw;
        dw = v.y - v.x; aW0 += dw * dw;
        dw = v.z - v.y; aW1 += dw * dw;
        dw = v.w - v.z; aW2 += dw * dw;
        if (sOK) { dw = sb - v.w; aW3 += dw * dw; }
        if (hok) aH[j] += sq4(hv, v);
        if (hasNext) aD += sq4(nv, v);
    }

    // ---- flush: private LDS slots for H (transpose), atomics for W, reduce for D
#pragma unroll
    for (int j = 0; j < 20; ++j) ldsH[j][t] = aH[j];
    atomicAdd(&accW[c4 * 4 + 0], aW0);
    atomicAdd(&accW[c4 * 4 + 1], aW1);
    atomicAdd(&accW[c4 * 4 + 2], aW2);
    if (sOK) atomicAdd(&accW[c4 * 4 + 3], aW3);
    if (hasNext) {
        for (int off = 32; off > 0; off >>= 1) aD += __shfl_down(aD, off, 64);
        if ((t & 63) == 0) atomicAdd(&accD, aD);
    }
    __syncthreads();

    float* slot = ws + (size_t)(b * ND + d) * BLK_STRIDE;
    if (t == 0) slot[0] = accD;
    if (t < 160) {
        // H[row r]: sum over the 40 threads with t/40 == r%8 at j == r/8
        const int r = t;
        float s = 0.f;
        const float* src = &ldsH[r >> 3][(r & 7) * 40];
        for (int i = 0; i < 40; ++i) s += src[i];
        slot[1 + r] = s;              // r=159 slot stays 0 (guarded), unused
    }
    if (t >= 160) slot[161 + (t - 160)] = accW[t - 160];
}

// 60 blocks x 64 threads: one thread per (axis, b, pair-key); H/W sum over d.
__global__ __launch_bounds__(64) void reduce_kernel(const float* __restrict__ ws,
                                                    const float* __restrict__ log_sigma,
                                                    float* __restrict__ part) {
    const int gk = blockIdx.x * 64 + threadIdx.x;
    float kv = 0.f;
    if (gk < NKEY) {
        const int a = gk / (NB * NPAIR);
        const int rem = gk % (NB * NPAIR);
        const int b = rem / NPAIR;
        const int key = rem % NPAIR;
        const float f = -0.5f * expf(-2.f * log_sigma[a]);  // -1/(2*sigma^2)
        const float* base = ws + (size_t)b * ND * BLK_STRIDE;
        float val;
        if (a == 0) {
            val = base[(size_t)key * BLK_STRIDE];            // block (b,key) owns pair
        } else {
            const int off = (a == 1) ? (1 + key) : (161 + key);
            val = 0.f;
            for (int d2 = 0; d2 < ND; ++d2) val += base[d2 * BLK_STRIDE + off];
        }
        kv = expf(val * f);
    }
    for (int off = 32; off > 0; off >>= 1) kv += __shfl_down(kv, off, 64);
    if (threadIdx.x == 0) part[blockIdx.x] = kv;
}

__global__ __launch_bounds__(64) void final_kernel(const float* __restrict__ part,
                                                   float* __restrict__ out) {
    float v = (threadIdx.x < NFIN) ? part[threadIdx.x] : 0.f;
    for (int off = 32; off > 0; off >>= 1) v += __shfl_down(v, off, 64);
    if (threadIdx.x == 0) out[0] = -v / (float)NKEY;
}

extern "C" void kernel_launch(void* const* d_in, const int* in_sizes, int n_in,
                              void* d_out, int out_size, void* d_ws, size_t ws_size,
                              hipStream_t stream) {
    const float* x = (const float*)d_in[0];
    const float* log_sigma = (const float*)d_in[1];
    float* out = (float*)d_out;
    float* ws = (float*)d_ws;

    diff3_kernel<<<NBLK, 320, 0, stream>>>(x, ws);
    reduce_kernel<<<NFIN, 64, 0, stream>>>(ws, log_sigma, ws + PART_OFF);
    final_kernel<<<1, 64, 0, stream>>>(ws + PART_OFF, out);
}

// Round 6
// 195.872 us; speedup vs baseline: 1.2078x; 1.2078x over previous
//
#include <hip/hip_runtime.h>

// x: [8, 1, 160, 160, 160] fp32; log_sigma: [3] fp32; out: scalar fp32.
// loss = -(sum over 3816 (axis,b,pair) of exp(-sq/(2*sigma_axis^2))) / 3816.
//
// R6: MINIMUM-WORK kernel. R1-R5 (5 structures: barriers, pipelining,
// barrier-free, full-unroll, pure-streaming) all ran 76-95us with VALUBusy
// 7-11%, Occ 13.5% — duration tracked only total instruction count, not
// structure or bytes. Hypothesis: work-bound at externally-fixed low clock.
// => minimize loads (29/thread vs 64-80) and VALU. Thread owns 4 CONSECUTIVE
// rows x 1 float4-col x 5 slices: 3/4 h-pairs register-local; w-boundary via
// __shfl_down (no loads); d via rolling regs + 1 halo slice per 5. Private
// per-block ws slots — no global atomics, no zeroing kernel.

constexpr int Wd4 = 40;              // float4 per row
constexpr int SLICE4 = 6400;         // float4 per slice
constexpr long BSTR4 = 160L * 6400;  // float4 per batch
constexpr int NB = 8;
constexpr int NPAIR = 159;
constexpr int NKEY = 3 * NB * NPAIR;   // 3816
constexpr int SLOT = 200;              // floats/slot: [0..4]=D [5..36]=H [37..196]=W
constexpr int NBLK = NB * 160;         // 8 b x 32 d-segs x 5 h-chunks = 1280
constexpr int PART_OFF = NBLK * SLOT;  // float offset of reduce partials in ws
constexpr int NFIN = 60;

__device__ __forceinline__ float sq4(const float4& a, const float4& c) {
    float e0 = a.x - c.x, e1 = a.y - c.y, e2 = a.z - c.z, e3 = a.w - c.w;
    return e0 * e0 + e1 * e1 + e2 * e2 + e3 * e3;
}

// 1280 blocks x 320 threads. bid -> (b, ds 0..31, hc 0..4). Thread: c4=t%40,
// rp=t/40 owns rows h0+4rp+{0..3}. Slices d0..d0+4 owned, d0+5 halo (v only).
__global__ __launch_bounds__(320) void diff3_kernel(const float* __restrict__ x,
                                                    float* __restrict__ ws) {
    __shared__ float lds[1504];  // H: [0..1311] 32 keys*41; D: [1472..1496]; W reuses [0..1439]

    const int t = threadIdx.x;
    const int bid = blockIdx.x;
    const int b = bid / 160;
    const int r2 = bid % 160;
    const int ds = r2 / 5;     // d-segment, d0 = 5*ds
    const int hc = r2 % 5;     // h-chunk,  h0 = 32*hc
    const int d0 = ds * 5, h0 = hc * 32;
    const bool lastSeg = (ds == 31);

    const int c4 = t % 40;
    const int rp = t / 40;                  // 0..7
    const int lane = t & 63;
    const int wv = t >> 6;                  // wave 0..4
    const bool hOK = !(hc == 4 && rp == 7); // row h0+4rp+4 <= 159
    const bool sOK = (c4 < 39);
    const bool fixB = (lane == 63) && sOK;  // shfl partner in next wave -> load

    const float4* base = (const float4*)x + (size_t)b * BSTR4 + (size_t)d0 * SLICE4
                       + (size_t)(h0 + 4 * rp) * Wd4 + c4;

    float aW[4] = {0.f, 0.f, 0.f, 0.f};
    float aH[4] = {0.f, 0.f, 0.f, 0.f};
    float aD[5] = {0.f, 0.f, 0.f, 0.f, 0.f};
    float4 p0, p1, p2, p3;

#pragma unroll
    for (int it = 0; it < 5; ++it) {
        const float4* sp = base + it * SLICE4;
        const float4 v0 = sp[0];
        const float4 v1 = sp[Wd4];
        const float4 v2 = sp[2 * Wd4];
        const float4 v3 = sp[3 * Wd4];
        float4 hv;
        if (hOK) hv = sp[4 * Wd4];
        float bx0 = 0.f, bx1 = 0.f, bx2 = 0.f, bx3 = 0.f;
        if (fixB) {  // cross-wave w-boundary partner: scalar loads (4 thr/block)
            bx0 = ((const float*)(sp))[4];
            bx1 = ((const float*)(sp + Wd4))[4];
            bx2 = ((const float*)(sp + 2 * Wd4))[4];
            bx3 = ((const float*)(sp + 3 * Wd4))[4];
        }
        // w-boundary partner .x from lane+1 (same row, next float4)
        float s0 = __shfl_down(v0.x, 1, 64); if (fixB) s0 = bx0;
        float s1 = __shfl_down(v1.x, 1, 64); if (fixB) s1 = bx1;
        float s2 = __shfl_down(v2.x, 1, 64); if (fixB) s2 = bx2;
        float s3 = __shfl_down(v3.x, 1, 64); if (fixB) s3 = bx3;

        float dw;
        dw = v0.y - v0.x; aW[0] += dw * dw;
        dw = v0.z - v0.y; aW[1] += dw * dw;
        dw = v0.w - v0.z; aW[2] += dw * dw;
        dw = v1.y - v1.x; aW[0] += dw * dw;
        dw = v1.z - v1.y; aW[1] += dw * dw;
        dw = v1.w - v1.z; aW[2] += dw * dw;
        dw = v2.y - v2.x; aW[0] += dw * dw;
        dw = v2.z - v2.y; aW[1] += dw * dw;
        dw = v2.w - v2.z; aW[2] += dw * dw;
        dw = v3.y - v3.x; aW[0] += dw * dw;
        dw = v3.z - v3.y; aW[1] += dw * dw;
        dw = v3.w - v3.z; aW[2] += dw * dw;
        if (sOK) {
            dw = s0 - v0.w; aW[3] += dw * dw;
            dw = s1 - v1.w; aW[3] += dw * dw;
            dw = s2 - v2.w; aW[3] += dw * dw;
            dw = s3 - v3.w; aW[3] += dw * dw;
        }
        // h: 3 register-local pairs + 1 via hv
        aH[0] += sq4(v1, v0);
        aH[1] += sq4(v2, v1);
        aH[2] += sq4(v3, v2);
        if (hOK) aH[3] += sq4(hv, v3);
        // d: vs previous slice (rolling regs)
        if (it > 0)
            aD[it - 1] += sq4(v0, p0) + sq4(v1, p1) + sq4(v2, p2) + sq4(v3, p3);
        p0 = v0; p1 = v1; p2 = v2; p3 = v3;  // SSA under full unroll
    }
    if (!lastSeg) {  // halo slice d0+5: v-only, completes pair key d0+4
        const float4* sp = base + 5 * SLICE4;
        aD[4] = sq4(sp[0], p0) + sq4(sp[Wd4], p1) + sq4(sp[2 * Wd4], p2) + sq4(sp[3 * Wd4], p3);
    }

    // ---- flush. Phase 1: H per-key scratch + D wave-reduce.
#pragma unroll
    for (int j = 0; j < 4; ++j) lds[(4 * rp + j) * 41 + c4] = aH[j];
#pragma unroll
    for (int j = 0; j < 5; ++j) {
        float dd = aD[j];
        for (int off = 32; off > 0; off >>= 1) dd += __shfl_down(dd, off, 64);
        if (lane == 0) lds[1472 + j * 5 + wv] = dd;
    }
    __syncthreads();
    float hsum = 0.f, dsum = 0.f;
    if (t < 32) {
        const float* src = &lds[t * 41];
        for (int i = 0; i < 40; ++i) hsum += src[i];
    }
    if (t < 5) {
        for (int w2 = 0; w2 < 5; ++w2) dsum += lds[1472 + t * 5 + w2];
    }
    __syncthreads();  // H region reads done; reuse for W
    // Phase 2: W per-key scratch (key 4c4+j, 8 contributors rp).
#pragma unroll
    for (int j = 0; j < 4; ++j) lds[(4 * c4 + j) * 9 + rp] = aW[j];
    __syncthreads();
    float wsum = 0.f;
    if (t < 160) {
        const float* src = &lds[t * 9];
        for (int i = 0; i < 8; ++i) wsum += src[i];
    }
    // Private slot write (no atomics; every slot float written).
    float* slot = ws + (size_t)bid * SLOT;
    if (t < 5)   slot[t] = dsum;
    if (t < 32)  slot[5 + t] = hsum;
    if (t < 160) slot[37 + t] = wsum;
}

// 60 blocks x 64 threads: one thread per (axis,b,pair); sums contributing slots.
__global__ __launch_bounds__(64) void reduce_kernel(const float* __restrict__ ws,
                                                    const float* __restrict__ log_sigma,
                                                    float* __restrict__ part) {
    const int gk = blockIdx.x * 64 + threadIdx.x;
    float kv = 0.f;
    if (gk < NKEY) {
        const int a = gk / (NB * NPAIR);
        const int rem = gk % (NB * NPAIR);
        const int b = rem / NPAIR;
        const int k = rem % NPAIR;
        const float f = -0.5f * expf(-2.f * log_sigma[a]);  // -1/(2*sigma^2)
        const float* bb = ws + (size_t)b * 160 * SLOT;
        float val = 0.f;
        if (a == 0) {        // D: key k -> ds=k/5, j=k%5, sum over 5 hc
            const int ds = k / 5, j = k % 5;
            const float* p = bb + (size_t)(ds * 5) * SLOT + j;
            for (int hc = 0; hc < 5; ++hc) val += p[hc * SLOT];
        } else if (a == 1) { // H: key k -> hc=k/32, kk=k%32, sum over 32 ds
            const int hc = k / 32, kk = k % 32;
            const float* p = bb + (size_t)hc * SLOT + 5 + kk;
            for (int ds = 0; ds < 32; ++ds) val += p[(size_t)(ds * 5) * SLOT];
        } else {             // W: key k, sum over all 160 (ds,hc)
            const float* p = bb + 37 + k;
            for (int i = 0; i < 160; ++i) val += p[(size_t)i * SLOT];
        }
        kv = expf(val * f);
    }
    for (int off = 32; off > 0; off >>= 1) kv += __shfl_down(kv, off, 64);
    if (threadIdx.x == 0) part[blockIdx.x] = kv;
}

__global__ __launch_bounds__(64) void final_kernel(const float* __restrict__ part,
                                                   float* __restrict__ out) {
    float v = (threadIdx.x < NFIN) ? part[threadIdx.x] : 0.f;
    for (int off = 32; off > 0; off >>= 1) v += __shfl_down(v, off, 64);
    if (threadIdx.x == 0) out[0] = -v / (float)NKEY;
}

extern "C" void kernel_launch(void* const* d_in, const int* in_sizes, int n_in,
                              void* d_out, int out_size, void* d_ws, size_t ws_size,
                              hipStream_t stream) {
    const float* x = (const float*)d_in[0];
    const float* log_sigma = (const float*)d_in[1];
    float* out = (float*)d_out;
    float* ws = (float*)d_ws;

    diff3_kernel<<<NBLK, 320, 0, stream>>>(x, ws);
    reduce_kernel<<<NFIN, 64, 0, stream>>>(ws, log_sigma, ws + PART_OFF);
    final_kernel<<<1, 64, 0, stream>>>(ws + PART_OFF, out);
}